// Round 1
// baseline (196.911 us; speedup 1.0000x reference)
//
#include <hip/hip_runtime.h>
#include <math.h>

#define Bv 32
#define Cv 256
#define Hv 32
#define Wv 32
#define Pv 1024   // H*W
#define Tv 4
#define TSTRIDE (Bv * Cv * Pv)   // elements between T-slabs = 8388608

// Kernel 1: per (b, channel-chunk) partial reduction over channels.
// grid = (nch, B), block = 256 threads; thread t owns pixels [4t, 4t+4) via float4.
// Produces part1[chunk][b][p] = sum_c xm, part2[chunk][b][p] = sum_c xm^2,
// where xm = mean over T of x[t,b,c,p].
__global__ __launch_bounds__(256) void lss_partial(
    const float* __restrict__ x,
    float* __restrict__ part1,
    float* __restrict__ part2,
    int cc)   // channels per chunk
{
    const int chunk = blockIdx.x;
    const int b     = blockIdx.y;
    const int tid   = threadIdx.x;
    const int p4    = tid << 2;
    const int c0    = chunk * cc;

    float s1x = 0.f, s1y = 0.f, s1z = 0.f, s1w = 0.f;
    float s2x = 0.f, s2y = 0.f, s2z = 0.f, s2w = 0.f;

    const float* bp = x + ((size_t)b * Cv + c0) * Pv + p4;

    #pragma unroll 4
    for (int c = 0; c < cc; ++c) {
        const float4 v0 = *(const float4*)(bp);
        const float4 v1 = *(const float4*)(bp + (size_t)TSTRIDE);
        const float4 v2 = *(const float4*)(bp + (size_t)2 * TSTRIDE);
        const float4 v3 = *(const float4*)(bp + (size_t)3 * TSTRIDE);
        bp += Pv;

        const float mx = (v0.x + v1.x + v2.x + v3.x) * 0.25f;
        const float my = (v0.y + v1.y + v2.y + v3.y) * 0.25f;
        const float mz = (v0.z + v1.z + v2.z + v3.z) * 0.25f;
        const float mw = (v0.w + v1.w + v2.w + v3.w) * 0.25f;

        s1x += mx;  s2x += mx * mx;
        s1y += my;  s2y += my * my;
        s1z += mz;  s2z += mz * mz;
        s1w += mw;  s2w += mw * mw;
    }

    const size_t o = ((size_t)chunk * Bv + b) * Pv + p4;
    float4 r1; r1.x = s1x; r1.y = s1y; r1.z = s1z; r1.w = s1w;
    float4 r2; r2.x = s2x; r2.y = s2y; r2.z = s2z; r2.w = s2w;
    *(float4*)(part1 + o) = r1;
    *(float4*)(part2 + o) = r2;
}

// Kernel 2: one block per batch b, one thread per pixel p (1024 threads).
// Reduce partials, 3x3 zero-padded box sum via LDS halo tile, cosine sim,
// mask, softmax over the 1024 pixels.
__global__ __launch_bounds__(1024) void lss_final(
    const float* __restrict__ part1,
    const float* __restrict__ part2,
    const int*   __restrict__ mask,
    float*       __restrict__ out,
    int nch)
{
    const int b   = blockIdx.x;
    const int tid = threadIdx.x;           // p in [0, 1024)
    const int yy  = tid >> 5;
    const int xx  = tid & 31;

    __shared__ float cs[(Hv + 2) * (Wv + 2)];   // zero-haloed csum tile
    __shared__ float red[Pv];

    // Reduce channel-chunk partials.
    float s1 = 0.f, s2 = 0.f;
    for (int ch = 0; ch < nch; ++ch) {
        const size_t o = ((size_t)ch * Bv + b) * Pv + tid;
        s1 += part1[o];
        s2 += part2[o];
    }
    const float csum = s1;                 // sum_c xm
    const float nx   = sqrtf(s2);          // ||xm||_channels

    // Zero halo, then place interior.
    for (int i = tid; i < (Hv + 2) * (Wv + 2); i += Pv) cs[i] = 0.f;
    __syncthreads();
    cs[(yy + 1) * (Wv + 2) + (xx + 1)] = csum;
    __syncthreads();

    // 3x3 box sum / 9 (zero padding == 'same' conv with ones kernel).
    float lm = 0.f;
    #pragma unroll
    for (int dy = 0; dy < 3; ++dy)
        #pragma unroll
        for (int dx = 0; dx < 3; ++dx)
            lm += cs[(yy + dy) * (Wv + 2) + (xx + dx)];
    lm *= (1.0f / 9.0f);

    // cosine similarity: dot = lm*csum ; ny = sqrt(C)*|lm| = 16*|lm|
    const float ny  = 16.0f * fabsf(lm);
    const float sim = (lm * csum) / (fmaxf(nx, 1e-6f) * fmaxf(ny, 1e-6f));

    const float score = mask[b * Pv + tid] ? -INFINITY : -sim;

    // Softmax over 1024 pixels: max-reduce, exp, sum-reduce.
    red[tid] = score;
    __syncthreads();
    for (int s = Pv / 2; s > 0; s >>= 1) {
        if (tid < s) red[tid] = fmaxf(red[tid], red[tid + s]);
        __syncthreads();
    }
    const float m = red[0];
    __syncthreads();

    const float e = expf(score - m);       // exp(-inf - m) == 0 for masked
    red[tid] = e;
    __syncthreads();
    for (int s = Pv / 2; s > 0; s >>= 1) {
        if (tid < s) red[tid] += red[tid + s];
        __syncthreads();
    }
    const float denom = red[0];

    out[b * Pv + tid] = e / denom;
}

extern "C" void kernel_launch(void* const* d_in, const int* in_sizes, int n_in,
                              void* d_out, int out_size, void* d_ws, size_t ws_size,
                              hipStream_t stream) {
    const float* x    = (const float*)d_in[0];
    const int*   mask = (const int*)d_in[1];
    float*       out  = (float*)d_out;

    // Pick channel-chunk count that fits the workspace (needs nch*B*P*2 floats).
    int nch = 16;
    while (nch > 1 && (size_t)nch * Bv * Pv * 2 * sizeof(float) > ws_size) nch >>= 1;
    const int cc = Cv / nch;

    float* part1 = (float*)d_ws;
    float* part2 = part1 + (size_t)nch * Bv * Pv;

    dim3 g1(nch, Bv);
    lss_partial<<<g1, 256, 0, stream>>>(x, part1, part2, cc);
    lss_final<<<Bv, Pv, 0, stream>>>(part1, part2, mask, out, nch);
}